// Round 11
// baseline (86.864 us; speedup 1.0000x reference)
//
#include <hip/hip_runtime.h>
#include <stdint.h>

// ExpertLoRA: N=8192, Z=1024, H=2048, W=64, R=8, SCALE=1.0
// Round 10: champion (R6-kernel) structure + TB=32/TW=4 + hv-first issue.
//  - ALL expert weights via LDS (a1 32K linear; b1/a2 3-deep 8K chunks;
//    b2 both-sides-swizzled into a1's region after phase 1)
//  - 320 blocks @ 80 KB = 2 blocks/CU -> entire grid co-resident, no tail
//  - counted-vmcnt pipeline; hv prefetch issued BEFORE stage(kc+2) so its
//    consumption doesn't retire the 2-ahead stage (in-order vmcnt).

constexpr int Zd = 1024;
constexpr int Hd = 2048;
constexpr int Rr = 8;
constexpr int Wn = 64;
constexpr int TB = 32;           // tokens per block
constexpr int TW = 4;            // tokens per wave
constexpr int NT = 512;          // threads per block (8 waves)
constexpr int HC = 256;          // phase-2 H chunk (elements)
constexpr int NCHUNK = Hd / HC;  // 8
constexpr float kScale = 1.0f;

// ws layout (ints): [0]=n_blocks, [16..16+N)=order, then int4 block table.

__global__ __launch_bounds__(1024) void bucket_kernel(
    const int* __restrict__ a_idx, int N, int* __restrict__ ws)
{
    __shared__ int hist[Wn];
    __shared__ int cursor[Wn];
    const int t = threadIdx.x;
    if (t < Wn) hist[t] = 0;
    __syncthreads();
    for (int i = t; i < N / 4; i += 1024) {
        const int4 v = ((const int4*)a_idx)[i];
        atomicAdd(&hist[v.x], 1); atomicAdd(&hist[v.y], 1);
        atomicAdd(&hist[v.z], 1); atomicAdd(&hist[v.w], 1);
    }
    for (int i = (N & ~3) + t; i < N; i += 1024) atomicAdd(&hist[a_idx[i]], 1);
    __syncthreads();

    if (t < Wn) {                       // wave 0 does both prefix scans
        const int c = hist[t];
        int scan = c;
#pragma unroll
        for (int off = 1; off < 64; off <<= 1) {
            const int v = __shfl_up(scan, off, 64);
            if (t >= off) scan += v;
        }
        const int base = scan - c;

        const int nb_e = (c + TB - 1) / TB;
        int bs = nb_e;
#pragma unroll
        for (int off = 1; off < 64; off <<= 1) {
            const int v = __shfl_up(bs, off, 64);
            if (t >= off) bs += v;
        }
        const int bstart = bs - nb_e;
        if (t == Wn - 1) ws[0] = bs;
        cursor[t] = base;

        int4* btab = (int4*)(ws + 16 + N);
        for (int s = 0, k = 0; s < c; s += TB, ++k)
            btab[bstart + k] = make_int4(t, base + s, min(TB, c - s), 0);
    }
    __syncthreads();
    int* order = ws + 16;
    for (int i = t; i < N / 4; i += 1024) {
        const int4 v = ((const int4*)a_idx)[i];
        order[atomicAdd(&cursor[v.x], 1)] = 4 * i + 0;
        order[atomicAdd(&cursor[v.y], 1)] = 4 * i + 1;
        order[atomicAdd(&cursor[v.z], 1)] = 4 * i + 2;
        order[atomicAdd(&cursor[v.w], 1)] = 4 * i + 3;
    }
    for (int i = (N & ~3) + t; i < N; i += 1024)
        order[atomicAdd(&cursor[a_idx[i]], 1)] = i;
}

__device__ __forceinline__ float wave_allreduce(float v) {
#pragma unroll
    for (int off = 1; off < 64; off <<= 1)
        v += __shfl_xor(v, off, 64);
    return v;
}

__device__ __forceinline__ float dot8(const float* t, float4 w0, float4 w1) {
    return fmaf(t[0], w0.x, fmaf(t[1], w0.y, fmaf(t[2], w0.z, fmaf(t[3], w0.w,
           fmaf(t[4], w1.x, fmaf(t[5], w1.y, fmaf(t[6], w1.z, t[7] * w1.w)))))));
}

__device__ __forceinline__ float silu(float x) {
    return x * __builtin_amdgcn_rcpf(1.f + __expf(-x));
}

// XOR swizzle: involution on byte offsets (bits 4-6 ^= bits 7-9).
__device__ __forceinline__ int swz(int o) {
    return o ^ (((o >> 7) & 7) << 4);
}

// async global -> LDS, 16 B per lane. LDS dest is wave-uniform base
// (HW adds lane*16); global src is per-lane.
__device__ __forceinline__ void stage16(const void* g, void* l) {
    __builtin_amdgcn_global_load_lds(
        (const __attribute__((address_space(1))) uint32_t*)g,
        (__attribute__((address_space(3))) uint32_t*)l, 16, 0, 0);
}

// Counted waits + raw barrier (no compiler vmcnt(0) drain).
#define WAITVM(N) asm volatile("s_waitcnt vmcnt(" #N ")" ::: "memory")
#define SYNC()    asm volatile("s_waitcnt lgkmcnt(0)\ns_barrier" ::: "memory")

__global__ __launch_bounds__(NT, 4) void lora_main(
    const float* __restrict__ z,        // [N, Z]
    const float* __restrict__ h_pre,    // [N, H]
    const float* __restrict__ out_pre,  // [N, Z]
    const float* __restrict__ a1,       // [W, R, Z]
    const float* __restrict__ b1,       // [W, H, R]
    const float* __restrict__ a2,       // [W, R, H]
    const float* __restrict__ b2,       // [W, Z, R]
    float* __restrict__ out,            // [N, Z]
    const int* __restrict__ ws, int N)
{
    __shared__ float s_a1[Rr * Zd];      // 32 KB: a1 (phase 1), b2 (phase 3)
    __shared__ float s_b1[3][HC * Rr];   // 3 x 8 KB
    __shared__ float s_a2[3][Rr * HC];   // 3 x 8 KB

    const int cpx = gridDim.x >> 3;
    const int lb  = (blockIdx.x & 7) * cpx + (blockIdx.x >> 3);
    if (lb >= ws[0]) return;

    const int4 desc = ((const int4*)(ws + 16 + N))[lb];
    const int e = desc.x, start = desc.y, cnt = desc.z;
    const int* order = ws + 16;

    const int t    = threadIdx.x;
    const int wave = t >> 6;
    const int lane = t & 63;

    bool val[TW];
    int  tok[TW];
#pragma unroll
    for (int k = 0; k < TW; ++k) {
        const int idx = wave * TW + k;
        val[k] = (idx < cnt);
        tok[k] = order[start + (val[k] ? idx : 0)];
    }

    const char*  a1e = (const char*)(a1 + (size_t)e * (Rr * Zd));
    const char*  b1e = (const char*)(b1 + (size_t)e * (Hd * Rr));
    const float* a2e = a2 + (size_t)e * (Rr * Hd);
    const char*  b2e = (const char*)(b2 + (size_t)e * (Zd * Rr));

    // ---- prologue: stage a1 (4), chunk0 (2), chunk1 (2); hv0 prefetch ----
#pragma unroll
    for (int i = 0; i < 4; ++i) {
        const int o = (i * NT + t) * 16;
        stage16(a1e + o, (char*)s_a1 + (i * NT + wave * 64) * 16);
    }
#pragma unroll
    for (int c0 = 0; c0 < 2; ++c0) {
        stage16(b1e + (size_t)(c0 * HC) * Rr * 4 + swz(t * 16),
                (char*)s_b1[c0] + wave * 1024);
        stage16(a2e + wave * Hd + c0 * HC + lane * 4,
                (char*)s_a2[c0] + wave * 1024);
    }
    float4 hv[2][TW];                    // hv[kc&1] = current chunk's h_pre
#pragma unroll
    for (int k = 0; k < TW; ++k)
        hv[0][k] = *(const float4*)(h_pre + (size_t)tok[k] * Hd + 4 * lane);

    WAITVM(8);     // a1 landed; c0/c1 (4) + hv0 (4) may remain in flight
    SYNC();

    // ---------- Phase 1: t1[k][r] = sum_d z[tok,d] * a1[e,r,d] (LDS a1) ----
    float p[TW][Rr];
#pragma unroll
    for (int k = 0; k < TW; ++k)
#pragma unroll
        for (int r = 0; r < Rr; ++r) p[k][r] = 0.f;

#pragma unroll
    for (int i = 0; i < Zd / 4 / 64; ++i) {         // 4 iters
        const int c = lane + i * 64;
        float4 zv[TW];
#pragma unroll
        for (int k = 0; k < TW; ++k)
            zv[k] = *(const float4*)(z + (size_t)tok[k] * Zd + 4 * c);
#pragma unroll
        for (int r = 0; r < Rr; ++r) {
            const float4 w = *(const float4*)(s_a1 + r * Zd + 4 * c);
#pragma unroll
            for (int k = 0; k < TW; ++k)
                p[k][r] = fmaf(zv[k].x, w.x, fmaf(zv[k].y, w.y,
                          fmaf(zv[k].z, w.z, fmaf(zv[k].w, w.w, p[k][r]))));
        }
    }
    float t1[TW][Rr];
#pragma unroll
    for (int k = 0; k < TW; ++k)
#pragma unroll
        for (int r = 0; r < Rr; ++r) t1[k][r] = wave_allreduce(p[k][r]);

    SYNC();        // all waves done reading a1; safe to overwrite with b2

    // stage b2 into s_a1 region (4 ops, swizzled src) — overlaps phase 2
#pragma unroll
    for (int i = 0; i < 4; ++i) {
        const int o = (i * NT + t) * 16;
        stage16(b2e + swz(o), (char*)s_a1 + (i * NT + wave * 64) * 16);
    }

    // ---------- Phase 2: 8 chunks, 3-deep pipeline, hv-first issue ----------
    float q[TW][Rr];
#pragma unroll
    for (int k = 0; k < TW; ++k)
#pragma unroll
        for (int r = 0; r < Rr; ++r) q[k][r] = 0.f;

#pragma unroll
    for (int kc = 0; kc < NCHUNK; ++kc) {
        // Own stage(kc) must have landed. Outstanding newer than stage(kc):
        // kc=0,1: pre-drained by phase 1 (no wait).
        // kc=2..6: hv(kc)[4] + stage(kc+1)[2] = 6.
        // kc=7:    hv(7)[4] = 4.
        if (kc >= 2 && kc < 7) { WAITVM(6); }
        else if (kc == 7)      { WAITVM(4); }
        SYNC();    // all waves' stage(kc) landed; rotated-buf readers done

        if (kc + 1 < NCHUNK) {      // hv prefetch FIRST (older than stage)
            const int cc = (kc + 1) * 64 + lane;
#pragma unroll
            for (int k = 0; k < TW; ++k)
                hv[(kc + 1) & 1][k] =
                    *(const float4*)(h_pre + (size_t)tok[k] * Hd + 4 * cc);
        }
        if (kc + 2 < NCHUNK) {      // stage(kc+2), stays in flight 2 iters
            const int nb = (kc + 2) % 3;
            const int hb = (kc + 2) * HC;
            stage16(b1e + (size_t)hb * Rr * 4 + swz(t * 16),
                    (char*)s_b1[nb] + wave * 1024);
            stage16(a2e + wave * Hd + hb + lane * 4,
                    (char*)s_a2[nb] + wave * 1024);
        }

        const int cur = kc % 3;
        float sv[TW][4];
#pragma unroll
        for (int j = 0; j < 4; ++j) {
            const int o0 = lane * 128 + j * 32;     // row (4*lane+j) of chunk
            const float4 w0 = *(const float4*)((const char*)s_b1[cur] + swz(o0));
            const float4 w1 = *(const float4*)((const char*)s_b1[cur] + swz(o0 + 16));
#pragma unroll
            for (int k = 0; k < TW; ++k) {
                const float x = (&hv[kc & 1][k].x)[j] + dot8(t1[k], w0, w1) * kScale;
                sv[k][j] = silu(x);
            }
        }
#pragma unroll
        for (int r = 0; r < Rr; ++r) {
            const float4 aw = *(const float4*)(s_a2[cur] + r * HC + lane * 4);
#pragma unroll
            for (int k = 0; k < TW; ++k)
                q[k][r] = fmaf(sv[k][0], aw.x, fmaf(sv[k][1], aw.y,
                          fmaf(sv[k][2], aw.z, fmaf(sv[k][3], aw.w, q[k][r]))));
        }
    }

    float t2[TW][Rr];
#pragma unroll
    for (int k = 0; k < TW; ++k)
#pragma unroll
        for (int r = 0; r < Rr; ++r) t2[k][r] = wave_allreduce(q[k][r]) * kScale;

    WAITVM(0);     // b2 fully landed (long since retired, cheap)
    SYNC();        // ... for every wave

    // ---------- Phase 3: out = out_pre + t2·b2[e,d,:]  (b2 in s_a1) ----------
#pragma unroll
    for (int i = 0; i < Zd / 4 / 64; ++i) {         // 4 iters
        const int c = lane + i * 64;
        float4 ov[TW];
#pragma unroll
        for (int k = 0; k < TW; ++k)
            ov[k] = *(const float4*)(out_pre + (size_t)tok[k] * Zd + 4 * c);
        float4 res[TW];
#pragma unroll
        for (int j = 0; j < 4; ++j) {
            const int o0 = c * 128 + j * 32;        // row (4c+j), 32 B each
            const float4 w0 = *(const float4*)((const char*)s_a1 + swz(o0));
            const float4 w1 = *(const float4*)((const char*)s_a1 + swz(o0 + 16));
#pragma unroll
            for (int k = 0; k < TW; ++k)
                (&res[k].x)[j] = (&ov[k].x)[j] + dot8(t2[k], w0, w1);
        }
#pragma unroll
        for (int k = 0; k < TW; ++k)
            if (val[k]) *(float4*)(out + (size_t)tok[k] * Zd + 4 * c) = res[k];
    }
}

extern "C" void kernel_launch(void* const* d_in, const int* in_sizes, int n_in,
                              void* d_out, int out_size, void* d_ws, size_t ws_size,
                              hipStream_t stream) {
    const float* z       = (const float*)d_in[0];
    const int*   a_idx   = (const int*)d_in[1];
    const float* h_pre   = (const float*)d_in[2];
    const float* out_pre = (const float*)d_in[3];
    const float* a1      = (const float*)d_in[4];
    const float* b1      = (const float*)d_in[5];
    const float* a2      = (const float*)d_in[6];
    const float* b2      = (const float*)d_in[7];
    float* out = (float*)d_out;

    const int N = in_sizes[1];  // a_idx count

    bucket_kernel<<<1, 1024, 0, stream>>>(a_idx, N, (int*)d_ws);

    int nwg = N / TB + Wn;              // 320 blocks (incl. per-expert tails)
    nwg = (nwg + 7) & ~7;               // multiple of 8 for XCD swizzle
    lora_main<<<nwg, NT, 0, stream>>>(z, h_pre, out_pre, a1, b1, a2, b2, out,
                                      (const int*)d_ws, N);
}

// Round 12
// 60.929 us; speedup vs baseline: 1.4257x; 1.4257x over previous
//
#include <hip/hip_runtime.h>
#include <stdint.h>

// ExpertLoRA: N=8192, Z=1024, H=2048, W=64, R=8, SCALE=1.0
// Round 11: champion (R7-bench) schedule with LDS 80->48 KB via slot pool:
//  pool = 6 x 8 KB slots. a1 in slots 0-3 (phase 1 only); chunk rotation
//  buf0={4,5} buf1={0,1} buf2={2,3}; b2 staged into slots freed at kc=6/7
//  (contiguous swizzled 32 KB at pool+16K for phase 3).
//  3 blocks/CU -> all 576 blocks co-resident, no tail dispatch round.
//  hv-first issue; uniform WAITVM(4) per chunk (derived, in-order vmcnt).

constexpr int Zd = 1024;
constexpr int Hd = 2048;
constexpr int Rr = 8;
constexpr int Wn = 64;
constexpr int TB = 16;           // tokens per block
constexpr int TW = 2;            // tokens per wave
constexpr int NT = 512;          // threads per block (8 waves)
constexpr int HC = 256;          // phase-2 H chunk (elements)
constexpr int NCHUNK = Hd / HC;  // 8
constexpr float kScale = 1.0f;

// ws layout (ints): [0]=n_blocks, [16..16+N)=order, then int4 block table.

__global__ __launch_bounds__(1024) void bucket_kernel(
    const int* __restrict__ a_idx, int N, int* __restrict__ ws)
{
    __shared__ int hist[Wn];
    __shared__ int cursor[Wn];
    const int t = threadIdx.x;
    if (t < Wn) hist[t] = 0;
    __syncthreads();
    for (int i = t; i < N / 4; i += 1024) {
        const int4 v = ((const int4*)a_idx)[i];
        atomicAdd(&hist[v.x], 1); atomicAdd(&hist[v.y], 1);
        atomicAdd(&hist[v.z], 1); atomicAdd(&hist[v.w], 1);
    }
    for (int i = (N & ~3) + t; i < N; i += 1024) atomicAdd(&hist[a_idx[i]], 1);
    __syncthreads();

    if (t < Wn) {                       // wave 0 does both prefix scans
        const int c = hist[t];
        int scan = c;
#pragma unroll
        for (int off = 1; off < 64; off <<= 1) {
            const int v = __shfl_up(scan, off, 64);
            if (t >= off) scan += v;
        }
        const int base = scan - c;

        const int nb_e = (c + TB - 1) / TB;
        int bs = nb_e;
#pragma unroll
        for (int off = 1; off < 64; off <<= 1) {
            const int v = __shfl_up(bs, off, 64);
            if (t >= off) bs += v;
        }
        const int bstart = bs - nb_e;
        if (t == Wn - 1) ws[0] = bs;
        cursor[t] = base;

        int4* btab = (int4*)(ws + 16 + N);
        for (int s = 0, k = 0; s < c; s += TB, ++k)
            btab[bstart + k] = make_int4(t, base + s, min(TB, c - s), 0);
    }
    __syncthreads();
    int* order = ws + 16;
    for (int i = t; i < N / 4; i += 1024) {
        const int4 v = ((const int4*)a_idx)[i];
        order[atomicAdd(&cursor[v.x], 1)] = 4 * i + 0;
        order[atomicAdd(&cursor[v.y], 1)] = 4 * i + 1;
        order[atomicAdd(&cursor[v.z], 1)] = 4 * i + 2;
        order[atomicAdd(&cursor[v.w], 1)] = 4 * i + 3;
    }
    for (int i = (N & ~3) + t; i < N; i += 1024)
        order[atomicAdd(&cursor[a_idx[i]], 1)] = i;
}

__device__ __forceinline__ float wave_allreduce(float v) {
#pragma unroll
    for (int off = 1; off < 64; off <<= 1)
        v += __shfl_xor(v, off, 64);
    return v;
}

__device__ __forceinline__ float dot8(const float* t, float4 w0, float4 w1) {
    return fmaf(t[0], w0.x, fmaf(t[1], w0.y, fmaf(t[2], w0.z, fmaf(t[3], w0.w,
           fmaf(t[4], w1.x, fmaf(t[5], w1.y, fmaf(t[6], w1.z, t[7] * w1.w)))))));
}

__device__ __forceinline__ float silu(float x) {
    return x * __builtin_amdgcn_rcpf(1.f + __expf(-x));
}

// XOR swizzle: involution on byte offsets (bits 4-6 ^= bits 7-9).
__device__ __forceinline__ int swz(int o) {
    return o ^ (((o >> 7) & 7) << 4);
}

// async global -> LDS, 16 B per lane. LDS dest is wave-uniform base
// (HW adds lane*16); global src is per-lane.
__device__ __forceinline__ void stage16(const void* g, void* l) {
    __builtin_amdgcn_global_load_lds(
        (const __attribute__((address_space(1))) uint32_t*)g,
        (__attribute__((address_space(3))) uint32_t*)l, 16, 0, 0);
}

// Counted waits + raw barrier (no compiler vmcnt(0) drain).
#define WAITVM(N) asm volatile("s_waitcnt vmcnt(" #N ")" ::: "memory")
#define SYNC()    asm volatile("s_waitcnt lgkmcnt(0)\ns_barrier" ::: "memory")

__global__ __launch_bounds__(NT, 6) void lora_main(
    const float* __restrict__ z,        // [N, Z]
    const float* __restrict__ h_pre,    // [N, H]
    const float* __restrict__ out_pre,  // [N, Z]
    const float* __restrict__ a1,       // [W, R, Z]
    const float* __restrict__ b1,       // [W, H, R]
    const float* __restrict__ a2,       // [W, R, H]
    const float* __restrict__ b2,       // [W, Z, R]
    float* __restrict__ out,            // [N, Z]
    const int* __restrict__ ws, int N)
{
    // 48 KB pool, six 8 KB slots.
    //  phase 1: a1 linear in bytes [0,32K) (slots 0-3); chunk0 in slots 4-5.
    //  phase 2: buf[b]: b1 base B1B[b], a2 base A2B[b] (8 KB each).
    //  phase 3: b2 contiguous swizzled in bytes [16K,48K).
    __shared__ float4 s_pool[3072];
    char* pool = (char*)s_pool;
    constexpr int B1B[3] = {32768, 0,    16384};
    constexpr int A2B[3] = {40960, 8192, 24576};

    const int cpx = gridDim.x >> 3;
    const int lb  = (blockIdx.x & 7) * cpx + (blockIdx.x >> 3);
    if (lb >= ws[0]) return;

    const int4 desc = ((const int4*)(ws + 16 + N))[lb];
    const int e = desc.x, start = desc.y, cnt = desc.z;
    const int* order = ws + 16;

    const int t    = threadIdx.x;
    const int wave = t >> 6;
    const int lane = t & 63;

    bool val[TW];
    int  tok[TW];
#pragma unroll
    for (int k = 0; k < TW; ++k) {
        const int idx = wave * TW + k;
        val[k] = (idx < cnt);
        tok[k] = order[start + (val[k] ? idx : 0)];
    }

    const char*  a1e = (const char*)(a1 + (size_t)e * (Rr * Zd));
    const char*  b1e = (const char*)(b1 + (size_t)e * (Hd * Rr));
    const float* a2e = a2 + (size_t)e * (Rr * Hd);
    const char*  b2e = (const char*)(b2 + (size_t)e * (Zd * Rr));

    // ---- prologue: a1 (4 ops) -> slots 0-3; chunk0 (2 ops) -> buf0; hv0 ----
#pragma unroll
    for (int i = 0; i < 4; ++i) {
        const int o = (i * NT + t) * 16;
        stage16(a1e + o, pool + i * 8192 + wave * 1024);
    }
    stage16(b1e + swz(t * 16),               pool + B1B[0] + wave * 1024);
    stage16(a2e + wave * Hd + lane * 4,      pool + A2B[0] + wave * 1024);
    float4 hv[2][TW];                    // hv[kc&1] = current chunk's h_pre
#pragma unroll
    for (int k = 0; k < TW; ++k)
        hv[0][k] = *(const float4*)(h_pre + (size_t)tok[k] * Hd + 4 * lane);

    WAITVM(4);     // a1 landed; chunk0 (2) + hv0 (2) may remain in flight
    SYNC();

    // ---------- Phase 1: t1[k][r] = sum_d z[tok,d] * a1[e,r,d] (LDS) ----
    float p[TW][Rr];
#pragma unroll
    for (int k = 0; k < TW; ++k)
#pragma unroll
        for (int r = 0; r < Rr; ++r) p[k][r] = 0.f;

#pragma unroll
    for (int i = 0; i < Zd / 4 / 64; ++i) {         // 4 iters
        const int c = lane + i * 64;
        float4 zv[TW];
#pragma unroll
        for (int k = 0; k < TW; ++k)
            zv[k] = *(const float4*)(z + (size_t)tok[k] * Zd + 4 * c);
#pragma unroll
        for (int r = 0; r < Rr; ++r) {
            const float4 w = *(const float4*)(pool + r * 4096 + c * 16);
#pragma unroll
            for (int k = 0; k < TW; ++k)
                p[k][r] = fmaf(zv[k].x, w.x, fmaf(zv[k].y, w.y,
                          fmaf(zv[k].z, w.z, fmaf(zv[k].w, w.w, p[k][r]))));
        }
    }
    float t1[TW][Rr];
#pragma unroll
    for (int k = 0; k < TW; ++k)
#pragma unroll
        for (int r = 0; r < Rr; ++r) t1[k][r] = wave_allreduce(p[k][r]);

    SYNC();        // all waves done reading a1; slots 0-3 join rotation

    // chunk1 -> buf1 (slots 0,1) — 2 ops
    stage16(b1e + (size_t)HC * Rr * 4 + swz(t * 16), pool + B1B[1] + wave * 1024);
    stage16(a2e + wave * Hd + HC + lane * 4,         pool + A2B[1] + wave * 1024);

    // ---------- Phase 2: 8 chunks, 3-buffer counted-vmcnt pipeline ----------
    float q[TW][Rr];
#pragma unroll
    for (int k = 0; k < TW; ++k)
#pragma unroll
        for (int r = 0; r < Rr; ++r) q[k][r] = 0.f;

#pragma unroll
    for (int kc = 0; kc < NCHUNK; ++kc) {
        // In-order vmcnt: at kc, outstanding = c(kc)[2] + hv(kc)[2] + c(kc+1)[2]
        // (older ops retired by phase-1 z-load waits / prior hv waits).
        // WAITVM(4) retires c(kc); kc=0 it is a no-op (c0 long landed).
        WAITVM(4);
        SYNC();    // all waves' stage(kc) landed; rotated buffer free

        if (kc + 1 < NCHUNK) {      // hv prefetch FIRST (stays oldest)
            const int cc = (kc + 1) * 64 + lane;
#pragma unroll
            for (int k = 0; k < TW; ++k)
                hv[(kc + 1) & 1][k] =
                    *(const float4*)(h_pre + (size_t)tok[k] * Hd + 4 * cc);
        }
        if (kc + 2 < NCHUNK) {      // chunk kc+2 -> buf (kc+2)%3
            const int nb = (kc + 2) % 3;
            const int hb = (kc + 2) * HC;
            stage16(b1e + (size_t)hb * Rr * 4 + swz(t * 16),
                    pool + B1B[nb] + wave * 1024);
            stage16(a2e + wave * Hd + hb + lane * 4,
                    pool + A2B[nb] + wave * 1024);
        } else {
            // kc=6: b2 bytes [0,16K) -> pool [16K,32K) (buf2 slots, freed)
            // kc=7: b2 bytes [16K,32K) -> pool [32K,48K) (buf0 slots, freed)
            const int half = kc - 6;            // 0 or 1
#pragma unroll
            for (int i = 0; i < 2; ++i) {
                const int g = half * 16384 + i * 8192;
                stage16(b2e + swz(g + t * 16),
                        pool + 16384 + g + wave * 1024);
            }
        }

        const int cb1 = B1B[kc % 3];
        const int ca2 = A2B[kc % 3];
        float sv[TW][4];
#pragma unroll
        for (int j = 0; j < 4; ++j) {
            const int o0 = lane * 128 + j * 32;     // row (4*lane+j) of chunk
            const float4 w0 = *(const float4*)(pool + cb1 + swz(o0));
            const float4 w1 = *(const float4*)(pool + cb1 + swz(o0 + 16));
#pragma unroll
            for (int k = 0; k < TW; ++k) {
                const float x = (&hv[kc & 1][k].x)[j] + dot8(t1[k], w0, w1) * kScale;
                sv[k][j] = silu(x);
            }
        }
#pragma unroll
        for (int r = 0; r < Rr; ++r) {
            const float4 aw = *(const float4*)(pool + ca2 + r * 1024 + lane * 16);
#pragma unroll
            for (int k = 0; k < TW; ++k)
                q[k][r] = fmaf(sv[k][0], aw.x, fmaf(sv[k][1], aw.y,
                          fmaf(sv[k][2], aw.z, fmaf(sv[k][3], aw.w, q[k][r]))));
        }
    }

    float t2[TW][Rr];
#pragma unroll
    for (int k = 0; k < TW; ++k)
#pragma unroll
        for (int r = 0; r < Rr; ++r) t2[k][r] = wave_allreduce(q[k][r]) * kScale;

    WAITVM(0);     // b2 halves landed (kc=7's half partially covered)
    SYNC();        // ... for every wave

    // ---------- Phase 3: out = out_pre + t2·b2  (b2 at pool+16K, swz) ------
#pragma unroll
    for (int i = 0; i < Zd / 4 / 64; ++i) {         // 4 iters
        const int c = lane + i * 64;
        float4 ov[TW];
#pragma unroll
        for (int k = 0; k < TW; ++k)
            ov[k] = *(const float4*)(out_pre + (size_t)tok[k] * Zd + 4 * c);
        float4 res[TW];
#pragma unroll
        for (int j = 0; j < 4; ++j) {
            const int o0 = c * 128 + j * 32;        // row (4c+j), 32 B each
            const float4 w0 = *(const float4*)(pool + 16384 + swz(o0));
            const float4 w1 = *(const float4*)(pool + 16384 + swz(o0 + 16));
#pragma unroll
            for (int k = 0; k < TW; ++k)
                (&res[k].x)[j] = (&ov[k].x)[j] + dot8(t2[k], w0, w1);
        }
#pragma unroll
        for (int k = 0; k < TW; ++k)
            if (val[k]) *(float4*)(out + (size_t)tok[k] * Zd + 4 * c) = res[k];
    }
}

extern "C" void kernel_launch(void* const* d_in, const int* in_sizes, int n_in,
                              void* d_out, int out_size, void* d_ws, size_t ws_size,
                              hipStream_t stream) {
    const float* z       = (const float*)d_in[0];
    const int*   a_idx   = (const int*)d_in[1];
    const float* h_pre   = (const float*)d_in[2];
    const float* out_pre = (const float*)d_in[3];
    const float* a1      = (const float*)d_in[4];
    const float* b1      = (const float*)d_in[5];
    const float* a2      = (const float*)d_in[6];
    const float* b2      = (const float*)d_in[7];
    float* out = (float*)d_out;

    const int N = in_sizes[1];  // a_idx count

    bucket_kernel<<<1, 1024, 0, stream>>>(a_idx, N, (int*)d_ws);

    int nwg = N / TB + Wn;              // 576 blocks (incl. per-expert tails)
    nwg = (nwg + 7) & ~7;               // multiple of 8 for XCD swizzle
    lora_main<<<nwg, NT, 0, stream>>>(z, h_pre, out_pre, a1, b1, a2, b2, out,
                                      (const int*)d_ws, N);
}